// Round 9
// baseline (136.638 us; speedup 1.0000x reference)
//
#include <hip/hip_runtime.h>

// Reprojection residual for bundle adjustment.
// out[i] = project(points_3d[pt_idx[i]], camera_params[cam_idx[i]]) - points_2d[i]
//
// NUMERICS: harness reference is float64; output is amplified ~proj^5 with
// |Z| down to ~1e-4, so the projection runs in double precision and only the
// final residual rounds to fp32 (absmax 3.60288e16 vs threshold 9.9e16,
// passing since round 2). The f64 op sequence below is frozen.
//
// ROUND 9: single-variable experiment — point gather 3 x dword -> 1 x
// under-aligned dwordx4 (ext_vector aligned(4); dword-family loads need only
// 4-B alignment on CDNA). TA coalesces same-line lanes within ONE
// instruction but cannot merge across the 3 dwords of a record, so this
// cuts gather address-path probes ~3x -> ~1.2x per point. The camera path's
// identical transition (5 divergent loads -> LDS) was the biggest win so
// far; this applies the same principle to the point path without the
// round-4 repack kernel's +10us/call cost. Final-record 4-B overread is
// handled by clamping the base and component-selecting (uniform cndmask,
// no divergence). All else frozen from round 8 (LDS cams, SWP depth-1,
// 512 persistent blocks, NT stream loads, plain cached stores).
//
// Inputs (setup_inputs order):
//   d_in[0] points_2d      float32 (N_OBS, 2)
//   d_in[1] camera_indices int32   (N_OBS,)
//   d_in[2] point_indices  int32   (N_OBS,)
//   d_in[3] camera_params  float32 (N_CAM, 10)  [qw qx qy qz tx ty tz f k1 k2]
//   d_in[4] points_3d      float32 (N_PTS, 3)
// Output: float32 (N_OBS, 2)

typedef __attribute__((ext_vector_type(4))) float f32x4;
typedef __attribute__((ext_vector_type(4), aligned(4))) float f32x4u;  // 4-B-aligned vector load
typedef __attribute__((ext_vector_type(2))) int   i32x2;

#define MAX_CAM_WORDS 20000   // 2000 cameras * 10 floats = 80 KB LDS

// Gather one 12-B point record with a single dwordx4 (4-B aligned is legal
// for dword-family on CDNA). Clamp so the 16-B window stays inside the
// table; select shifted components for the (rare) clamped case.
__device__ __forceinline__ void gather_point(
    const float* __restrict__ pts, int pi, int npts3,
    float& x, float& y, float& z)
{
    int base = pi * 3;
    bool clamped = (base + 4 > npts3);
    int b = clamped ? (npts3 - 4) : base;
    f32x4u v = *reinterpret_cast<const f32x4u*>(pts + b);
    x = clamped ? v.y : v.x;
    y = clamped ? v.z : v.y;
    z = clamped ? v.w : v.z;
}

// f64 projection; camera params from LDS. Frozen arithmetic sequence.
__device__ __forceinline__ float2 project_one(
    const float* lds_cams, int ci,
    float pxf, float pyf, float pzf,
    float obsx, float obsy)
{
    const float2* cl = reinterpret_cast<const float2*>(lds_cams + ci * 10);
    float2 c01 = cl[0];  // qw qx
    float2 c23 = cl[1];  // qy qz
    float2 c45 = cl[2];  // tx ty
    float2 c67 = cl[3];  // tz f
    float2 c89 = cl[4];  // k1 k2

    double px = (double)pxf, py = (double)pyf, pz = (double)pzf;
    double qw = (double)c01.x, qx = (double)c01.y;
    double qy = (double)c23.x, qz = (double)c23.y;

    double nrm2 = qw * qw + qx * qx + qy * qy + qz * qz;
    double s = 1.0 / sqrt(nrm2);
    double w  = qw * s;
    double vx = qx * s, vy = qy * s, vz = qz * s;

    double tx = (vy * pz - vz * py) + w * px;
    double ty = (vz * px - vx * pz) + w * py;
    double tz = (vx * py - vy * px) + w * pz;

    double X = (px + 2.0 * (vy * tz - vz * ty)) + (double)c45.x;
    double Y = (py + 2.0 * (vz * tx - vx * tz)) + (double)c45.y;
    double Z = (pz + 2.0 * (vx * ty - vy * tx)) + (double)c67.x;

    double rz  = 1.0 / Z;
    double prx = -X * rz;
    double pry = -Y * rz;

    double f  = (double)c67.y;
    double k1 = (double)c89.x, k2 = (double)c89.y;

    double nn = prx * prx + pry * pry;
    double r  = 1.0 + k1 * nn + k2 * nn * nn;
    double rf = r * f;

    float2 o;
    o.x = (float)(prx * rf - (double)obsx);
    o.y = (float)(pry * rf - (double)obsy);
    return o;
}

__global__ __launch_bounds__(1024, 8) void reproj_kernel(
    const f32x4*  __restrict__ p2d4,      // 2 observations per float4
    const int*    __restrict__ cam_idx,
    const int*    __restrict__ pt_idx,
    const float*  __restrict__ cams,
    const float*  __restrict__ pts,       // raw (N_PTS,3) float32
    f32x4*        __restrict__ out4,
    int n, int ncam_words, int npts3)
{
    __shared__ float lds_cams[MAX_CAM_WORDS];

    // cooperative stage: 80 KB, coalesced float4 loads + b128 LDS writes
    {
        int nv = ncam_words >> 2;
        if (nv > (MAX_CAM_WORDS >> 2)) nv = MAX_CAM_WORDS >> 2;
        const f32x4* src = reinterpret_cast<const f32x4*>(cams);
        f32x4* dst = reinterpret_cast<f32x4*>(lds_cams);
        for (int j = threadIdx.x; j < nv; j += blockDim.x)
            dst[j] = src[j];
        for (int j = (nv << 2) + threadIdx.x; j < ncam_words && j < MAX_CAM_WORDS;
             j += blockDim.x)
            lds_cams[j] = cams[j];
    }
    __syncthreads();

    const int stride = gridDim.x * blockDim.x * 2;   // obs per sweep
    int i = (blockIdx.x * blockDim.x + threadIdx.x) * 2;

    // ---- pipeline prologue: load iteration-0 inputs ----
    i32x2 ci, pi;
    f32x4 ob;
    float ax, ay, az, bx, by, bz;
    if (i + 1 < n) {
        ci = __builtin_nontemporal_load(
            reinterpret_cast<const i32x2*>(cam_idx + i));
        pi = __builtin_nontemporal_load(
            reinterpret_cast<const i32x2*>(pt_idx + i));
        ob = __builtin_nontemporal_load(p2d4 + (i >> 1));
        gather_point(pts, pi.x, npts3, ax, ay, az);
        gather_point(pts, pi.y, npts3, bx, by, bz);
    }

    while (i + 1 < n) {
        int j = i + stride;

        // ---- issue next iteration's loads BEFORE current compute ----
        i32x2 cin, pin;
        f32x4 obn;
        float nax, nay, naz, nbx, nby, nbz;
        bool nhave = (j + 1 < n);
        if (nhave) {
            cin = __builtin_nontemporal_load(
                reinterpret_cast<const i32x2*>(cam_idx + j));
            pin = __builtin_nontemporal_load(
                reinterpret_cast<const i32x2*>(pt_idx + j));
            obn = __builtin_nontemporal_load(p2d4 + (j >> 1));
            gather_point(pts, pin.x, npts3, nax, nay, naz);
            gather_point(pts, pin.y, npts3, nbx, nby, nbz);
        }

        // ---- compute current iteration (hides next loads' latency) ----
        float2 o0 = project_one(lds_cams, ci.x, ax, ay, az, ob.x, ob.y);
        float2 o1 = project_one(lds_cams, ci.y, bx, by, bz, ob.z, ob.w);
        f32x4 ov = {o0.x, o0.y, o1.x, o1.y};
        out4[i >> 1] = ov;   // plain cached store: L2 write-combines

        // ---- rotate pipeline ----
        i = j;
        if (nhave) {
            ci = cin; pi = pin; ob = obn;
            ax = nax; ay = nay; az = naz;
            bx = nbx; by = nby; bz = nbz;
        }
    }

    // tail: single trailing observation (odd n)
    if (i < n) {
        int cis = cam_idx[i];
        int pis = pt_idx[i];
        float ax2, ay2, az2;
        gather_point(pts, pis, npts3, ax2, ay2, az2);
        const float* p2 = reinterpret_cast<const float*>(p2d4);
        float2 o = project_one(lds_cams, cis, ax2, ay2, az2,
                               p2[2 * i], p2[2 * i + 1]);
        float* po = reinterpret_cast<float*>(out4);
        po[2 * i]     = o.x;
        po[2 * i + 1] = o.y;
    }
}

extern "C" void kernel_launch(void* const* d_in, const int* in_sizes, int n_in,
                              void* d_out, int out_size, void* d_ws, size_t ws_size,
                              hipStream_t stream) {
    const float* p2d     = (const float*)d_in[0];
    const int*   cam_idx = (const int*)d_in[1];
    const int*   pt_idx  = (const int*)d_in[2];
    const float* cams    = (const float*)d_in[3];
    const float* pts     = (const float*)d_in[4];

    int n     = in_sizes[1];  // N_OBS
    int ncw   = in_sizes[3];  // N_CAM * 10
    int npts3 = in_sizes[4];  // N_PTS * 3

    int threads = 1024;
    // persistent: 2 blocks/CU (80-KB LDS max) on 256 CUs
    int blocks = 512;
    int need = (n + threads * 2 - 1) / (threads * 2);
    if (need < blocks) blocks = need;
    if (blocks < 1) blocks = 1;

    reproj_kernel<<<blocks, threads, 0, stream>>>(
        (const f32x4*)p2d, cam_idx, pt_idx, cams, pts,
        (f32x4*)d_out, n, ncw, npts3);
}

// Round 10
// 133.287 us; speedup vs baseline: 1.0251x; 1.0251x over previous
//
#include <hip/hip_runtime.h>

// Reprojection residual for bundle adjustment.
// out[i] = project(points_3d[pt_idx[i]], camera_params[cam_idx[i]]) - points_2d[i]
//
// NUMERICS: the cancellation-sensitive part (quaternion normalize, rotation,
// translation -> X,Y,Z with |Z| down to ~1e-4) runs in float64. The epilogue
// (proj division, radial distortion, residual) runs in float32: once Z is
// f64-accurate, prx=-X/Z in f32 carries ~1.2e-7 rel error, amplified ~5x by
// the proj^5 polynomial -> ~1e-6 relative on out vs the 2% threshold.
// (Full-f64 passed rounds 2-9 with absmax 3.60288e16 vs threshold 9.9e16.)
//
// ROUND 10: revert round-9's dwordx4 gather (regressed: straddling 16-B
// windows added ~10 MB FETCH; 3-dword gather restored). Single change vs
// round-8's 132.8 us: f32 epilogue, removing the ~25-40-instruction f64
// division microcode (1/Z) from the per-obs dependent chain.
// Frozen structure: LDS camera table (80 KB), SWP depth-1 grid-stride,
// 512 persistent blocks x 1024 threads, NT streaming loads, plain stores.
//
// Inputs (setup_inputs order):
//   d_in[0] points_2d      float32 (N_OBS, 2)
//   d_in[1] camera_indices int32   (N_OBS,)
//   d_in[2] point_indices  int32   (N_OBS,)
//   d_in[3] camera_params  float32 (N_CAM, 10)  [qw qx qy qz tx ty tz f k1 k2]
//   d_in[4] points_3d      float32 (N_PTS, 3)
// Output: float32 (N_OBS, 2)

typedef __attribute__((ext_vector_type(4))) float f32x4;
typedef __attribute__((ext_vector_type(2))) int   i32x2;

#define MAX_CAM_WORDS 20000   // 2000 cameras * 10 floats = 80 KB LDS

// f64 rotation core + f32 epilogue; camera params from LDS.
__device__ __forceinline__ float2 project_one(
    const float* lds_cams, int ci,
    float pxf, float pyf, float pzf,
    float obsx, float obsy)
{
    const float2* cl = reinterpret_cast<const float2*>(lds_cams + ci * 10);
    float2 c01 = cl[0];  // qw qx
    float2 c23 = cl[1];  // qy qz
    float2 c45 = cl[2];  // tx ty
    float2 c67 = cl[3];  // tz f
    float2 c89 = cl[4];  // k1 k2

    double px = (double)pxf, py = (double)pyf, pz = (double)pzf;
    double qw = (double)c01.x, qx = (double)c01.y;
    double qy = (double)c23.x, qz = (double)c23.y;

    // f64: normalize quaternion (cancellation-critical path begins)
    double nrm2 = qw * qw + qx * qx + qy * qy + qz * qz;
    double s = 1.0 / sqrt(nrm2);
    double w  = qw * s;
    double vx = qx * s, vy = qy * s, vz = qz * s;

    // f64: t = cross(v, p) + w * p
    double tx = (vy * pz - vz * py) + w * px;
    double ty = (vz * px - vx * pz) + w * py;
    double tz = (vx * py - vy * px) + w * pz;

    // f64: rotated = p + 2 * cross(v, t); then translate
    double X = (px + 2.0 * (vy * tz - vz * ty)) + (double)c45.x;
    double Y = (py + 2.0 * (vz * tx - vx * tz)) + (double)c45.y;
    double Z = (pz + 2.0 * (vx * ty - vy * tx)) + (double)c67.x;

    // f32 epilogue: division, distortion, residual (error ~1e-6 relative)
    float Xf = (float)X, Yf = (float)Y, Zf = (float)Z;
    float prx = (-Xf) / Zf;
    float pry = (-Yf) / Zf;

    float f  = c67.y;
    float k1 = c89.x, k2 = c89.y;

    float nn = prx * prx + pry * pry;
    float r  = 1.0f + k1 * nn + k2 * nn * nn;
    float rf = r * f;

    float2 o;
    o.x = prx * rf - obsx;
    o.y = pry * rf - obsy;
    return o;
}

__global__ __launch_bounds__(1024, 8) void reproj_kernel(
    const f32x4*  __restrict__ p2d4,      // 2 observations per float4
    const int*    __restrict__ cam_idx,
    const int*    __restrict__ pt_idx,
    const float*  __restrict__ cams,
    const float*  __restrict__ pts,       // raw (N_PTS,3) float32
    f32x4*        __restrict__ out4,
    int n, int ncam_words)
{
    __shared__ float lds_cams[MAX_CAM_WORDS];

    // cooperative stage: 80 KB, coalesced float4 loads + b128 LDS writes
    {
        int nv = ncam_words >> 2;
        if (nv > (MAX_CAM_WORDS >> 2)) nv = MAX_CAM_WORDS >> 2;
        const f32x4* src = reinterpret_cast<const f32x4*>(cams);
        f32x4* dst = reinterpret_cast<f32x4*>(lds_cams);
        for (int j = threadIdx.x; j < nv; j += blockDim.x)
            dst[j] = src[j];
        for (int j = (nv << 2) + threadIdx.x; j < ncam_words && j < MAX_CAM_WORDS;
             j += blockDim.x)
            lds_cams[j] = cams[j];
    }
    __syncthreads();

    const int stride = gridDim.x * blockDim.x * 2;   // obs per sweep
    int i = (blockIdx.x * blockDim.x + threadIdx.x) * 2;

    // ---- pipeline prologue: load iteration-0 inputs ----
    i32x2 ci, pi;
    f32x4 ob;
    float ax, ay, az, bx, by, bz;
    if (i + 1 < n) {
        ci = __builtin_nontemporal_load(
            reinterpret_cast<const i32x2*>(cam_idx + i));
        pi = __builtin_nontemporal_load(
            reinterpret_cast<const i32x2*>(pt_idx + i));
        ob = __builtin_nontemporal_load(p2d4 + (i >> 1));
        const float* pA = pts + (size_t)pi.x * 3;
        const float* pB = pts + (size_t)pi.y * 3;
        ax = pA[0]; ay = pA[1]; az = pA[2];
        bx = pB[0]; by = pB[1]; bz = pB[2];
    }

    while (i + 1 < n) {
        int j = i + stride;

        // ---- issue next iteration's loads BEFORE current compute ----
        i32x2 cin, pin;
        f32x4 obn;
        float nax, nay, naz, nbx, nby, nbz;
        bool nhave = (j + 1 < n);
        if (nhave) {
            cin = __builtin_nontemporal_load(
                reinterpret_cast<const i32x2*>(cam_idx + j));
            pin = __builtin_nontemporal_load(
                reinterpret_cast<const i32x2*>(pt_idx + j));
            obn = __builtin_nontemporal_load(p2d4 + (j >> 1));
            const float* pA = pts + (size_t)pin.x * 3;
            const float* pB = pts + (size_t)pin.y * 3;
            nax = pA[0]; nay = pA[1]; naz = pA[2];
            nbx = pB[0]; nby = pB[1]; nbz = pB[2];
        }

        // ---- compute current iteration (hides next loads' latency) ----
        float2 o0 = project_one(lds_cams, ci.x, ax, ay, az, ob.x, ob.y);
        float2 o1 = project_one(lds_cams, ci.y, bx, by, bz, ob.z, ob.w);
        f32x4 ov = {o0.x, o0.y, o1.x, o1.y};
        out4[i >> 1] = ov;   // plain cached store: L2 write-combines

        // ---- rotate pipeline ----
        i = j;
        if (nhave) {
            ci = cin; pi = pin; ob = obn;
            ax = nax; ay = nay; az = naz;
            bx = nbx; by = nby; bz = nbz;
        }
    }

    // tail: single trailing observation (odd n)
    if (i < n) {
        int cis = cam_idx[i];
        int pis = pt_idx[i];
        const float* pA = pts + (size_t)pis * 3;
        const float* p2 = reinterpret_cast<const float*>(p2d4);
        float2 o = project_one(lds_cams, cis, pA[0], pA[1], pA[2],
                               p2[2 * i], p2[2 * i + 1]);
        float* po = reinterpret_cast<float*>(out4);
        po[2 * i]     = o.x;
        po[2 * i + 1] = o.y;
    }
}

extern "C" void kernel_launch(void* const* d_in, const int* in_sizes, int n_in,
                              void* d_out, int out_size, void* d_ws, size_t ws_size,
                              hipStream_t stream) {
    const float* p2d     = (const float*)d_in[0];
    const int*   cam_idx = (const int*)d_in[1];
    const int*   pt_idx  = (const int*)d_in[2];
    const float* cams    = (const float*)d_in[3];
    const float* pts     = (const float*)d_in[4];

    int n   = in_sizes[1];  // N_OBS
    int ncw = in_sizes[3];  // N_CAM * 10

    int threads = 1024;
    // persistent: 2 blocks/CU (80-KB LDS max) on 256 CUs
    int blocks = 512;
    int need = (n + threads * 2 - 1) / (threads * 2);
    if (need < blocks) blocks = need;
    if (blocks < 1) blocks = 1;

    reproj_kernel<<<blocks, threads, 0, stream>>>(
        (const f32x4*)p2d, cam_idx, pt_idx, cams, pts,
        (f32x4*)d_out, n, ncw);
}